// Round 8
// baseline (24.522 us; speedup 1.0000x reference)
//
#include <hip/hip_runtime.h>
#include <math.h>

// VoronoiDecoder: N=65536 x S=32. 8 lanes/point, 4 seeds/lane, 512-thr blocks,
// 64 points/block, grid=1024 (4 blocks/CU, 8 waves/SIMD).
// Pair sigmoid via Pade[7/6] tanh rational (integer coeffs, err<=5e-5 on the
// clamped range): 14 VALU + 1 v_rcp per pair, ZERO DS reads in the pair loop.
// LDS holds only the d/w exchange slabs (stride 40 words = 2-way banks, free)
// and the 32 seed metrics. No table, no table build.

#define LOG2E  1.4426950408889634f
#define EPSF   1e-8f
#define BLOCK  512
#define PPB    64               // points per block
#define SSTR   40               // slab row stride (words)

__global__ __launch_bounds__(BLOCK, 8) void voronoi_v8(
    const float* __restrict__ points,   // (N,2)
    const float* __restrict__ seeds,    // (32,2)
    const float* __restrict__ w_raw,    // (1,)
    const float* __restrict__ theta,    // (32,)
    const float* __restrict__ a_raw,    // (32,)
    float* __restrict__ out,            // (N,)
    int N)
{
    __shared__ float s_dd[PPB * SSTR];
    __shared__ float s_ww[PPB * SSTR];
    __shared__ float s_su[32], s_sv[32], s_m00[32], s_m01[32], s_m11[32];

    const int t = threadIdx.x;

    // uniform band half-width
    const float wr = w_raw[0];
    const float sg = __builtin_amdgcn_rcpf(1.0f + exp2f(wr * (-LOG2E / 5.0f)));
    const float w  = 0.005f + 0.495f * sg;
    const float wc = w * 25.0f;          // w/(2*beta)

    // seed metrics (natural units; 2x folded into m01)
    if (t < 32) {
        const float x  = a_raw[t];
        const float z  = exp2f(2.0f * LOG2E * x);
        const float th = (z - 1.0f) * __builtin_amdgcn_rcpf(z + 1.0f);  // tanh
        const float a  = 0.75f * th + 1.25f;
        const float ia = __builtin_amdgcn_rcpf(a + EPSF);
        const float cs = __cosf(theta[t]);
        const float sn = __sinf(theta[t]);
        s_m00[t] = a * cs * cs + ia * sn * sn;
        s_m01[t] = 2.0f * cs * sn * (ia - a);
        s_m11[t] = a * sn * sn + ia * cs * cs;
        s_su[t]  = seeds[2 * t];
        s_sv[t]  = seeds[2 * t + 1];
    }
    __syncthreads();   // only barrier; slab exchange below is same-wave

    const int pb = t >> 3;              // point slot (0..63)
    const int g  = t & 7;               // seed group
    const int s0 = g * 4;
    const int p  = blockIdx.x * PPB + pb;
    if (p >= N) return;

    const float4 su4  = *(const float4*)&s_su[s0];
    const float4 sv4  = *(const float4*)&s_sv[s0];
    const float4 m004 = *(const float4*)&s_m00[s0];
    const float4 m014 = *(const float4*)&s_m01[s0];
    const float4 m114 = *(const float4*)&s_m11[s0];

    const float2 uv = ((const float2*)points)[p];
    const float u = uv.x, v = uv.y;

    float4 d4;
#define DIST(SU, SV, M00, M01, M11, OUTD)                                  \
    {                                                                      \
        float du = u - (SU); du -= rintf(du);                              \
        float dv = v - (SV); dv -= rintf(dv);                              \
        float q = fmaf(du * du, (M00),                                     \
                  fmaf(du * dv, (M01),                                     \
                  fmaf(dv * dv, (M11), EPSF)));                            \
        (OUTD) = sqrtf(q);                                                 \
    }
    DIST(su4.x, sv4.x, m004.x, m014.x, m114.x, d4.x)
    DIST(su4.y, sv4.y, m004.y, m014.y, m114.y, d4.y)
    DIST(su4.z, sv4.z, m004.z, m014.z, m114.z, d4.z)
    DIST(su4.w, sv4.w, m004.w, m014.w, m114.w, d4.w)

    // softmax over 32 seeds (exponents bounded below ~ -29; no max-sub)
    const float cE = -20.0f * LOG2E;
    float4 e4;
    e4.x = exp2f(d4.x * cE);
    e4.y = exp2f(d4.y * cE);
    e4.z = exp2f(d4.z * cE);
    e4.w = exp2f(d4.w * cE);
    float Z = (e4.x + e4.y) + (e4.z + e4.w);
    Z += __shfl_xor(Z, 1, 64);
    Z += __shfl_xor(Z, 2, 64);
    Z += __shfl_xor(Z, 4, 64);
    const float rcpZ = __builtin_amdgcn_rcpf(Z);
    float4 w4;
    w4.x = e4.x * rcpZ; w4.y = e4.y * rcpZ;
    w4.z = e4.z * rcpZ; w4.w = e4.w * rcpZ;
    float sumsq = w4.x * w4.x;
    sumsq = fmaf(w4.y, w4.y, sumsq);
    sumsq = fmaf(w4.z, w4.z, sumsq);
    sumsq = fmaf(w4.w, w4.w, sumsq);

    // stage (d,w) to this point's slab row (same-wave exchange, no barrier)
    float* db = &s_dd[pb * SSTR];
    float* wb = &s_ww[pb * SSTR];
    *(float4*)(db + s0) = d4;
    *(float4*)(wb + s0) = w4;

    // pair body: B = sigmoid((w-|dI-dJ|)/beta) via 0.5+0.5*tanh(x), x clamped
    // tanh Pade[7/6]: x(135135+17325t+378t^2+t^3)/(135135+62370t+3150t^2+28t^3)
#define FBODY(DI, DJ, WJ, ACC)                                             \
    {                                                                      \
        const float ab = fabsf((DI) - (DJ));                               \
        float x = fmaf(ab, -25.0f, wc);                                    \
        x = fminf(fmaxf(x, -4.6f), 4.6f);                                  \
        const float tt = x * x;                                            \
        const float nm = fmaf(fmaf(tt + 378.0f, tt, 17325.0f), tt,         \
                              135135.0f);                                  \
        const float dn = fmaf(fmaf(fmaf(28.0f, tt, 3150.0f), tt,           \
                              62370.0f), tt, 135135.0f);                   \
        const float xr = x * __builtin_amdgcn_rcpf(dn);                    \
        const float B  = fmaf(nm * xr, 0.5f, 0.5f);                        \
        (ACC) = fmaf((WJ), B, (ACC));                                      \
    }

    // 6 in-lane pairs
    float b0, b1, b2, b3;
    b0 = 0.0f; b1 = 0.0f; b2 = 0.0f; b3 = 0.0f;
    FBODY(d4.x, d4.y, w4.y, b0)
    FBODY(d4.x, d4.z, w4.z, b0)
    FBODY(d4.x, d4.w, w4.w, b0)
    FBODY(d4.y, d4.z, w4.z, b1)
    FBODY(d4.y, d4.w, w4.w, b1)
    FBODY(d4.z, d4.w, w4.w, b2)

#define ROT(R, HALF)                                                       \
    {                                                                      \
        const int gj = ((g + (R)) & 7) * 4;                                \
        const float4 dj = *(const float4*)(db + gj);                       \
        float4 wj = *(const float4*)(wb + gj);                             \
        if (HALF) { wj.x *= 0.5f; wj.y *= 0.5f; wj.z *= 0.5f; wj.w *= 0.5f; } \
        FBODY(d4.x, dj.x, wj.x, b0)                                        \
        FBODY(d4.x, dj.y, wj.y, b0)                                        \
        FBODY(d4.x, dj.z, wj.z, b0)                                        \
        FBODY(d4.x, dj.w, wj.w, b0)                                        \
        FBODY(d4.y, dj.x, wj.x, b1)                                        \
        FBODY(d4.y, dj.y, wj.y, b1)                                        \
        FBODY(d4.y, dj.z, wj.z, b1)                                        \
        FBODY(d4.y, dj.w, wj.w, b1)                                        \
        FBODY(d4.z, dj.x, wj.x, b2)                                        \
        FBODY(d4.z, dj.y, wj.y, b2)                                        \
        FBODY(d4.z, dj.z, wj.z, b2)                                        \
        FBODY(d4.z, dj.w, wj.w, b2)                                        \
        FBODY(d4.w, dj.x, wj.x, b3)                                        \
        FBODY(d4.w, dj.y, wj.y, b3)                                        \
        FBODY(d4.w, dj.z, wj.z, b3)                                        \
        FBODY(d4.w, dj.w, wj.w, b3)                                        \
    }
    ROT(1, 0)
    ROT(2, 0)
    ROT(3, 0)
    ROT(4, 1)       // opposite group counted twice -> half weight

    float accb = w4.x * b0;
    accb = fmaf(w4.y, b1, accb);
    accb = fmaf(w4.z, b2, accb);
    accb = fmaf(w4.w, b3, accb);

    // reduce over the point's 8 lanes
    float nb = accb, sq = sumsq;
    nb += __shfl_xor(nb, 1, 64);  sq += __shfl_xor(sq, 1, 64);
    nb += __shfl_xor(nb, 2, 64);  sq += __shfl_xor(sq, 2, 64);
    nb += __shfl_xor(nb, 4, 64);  sq += __shfl_xor(sq, 4, 64);

    // pair mass: sum_{i<j} w_i w_j = (1 - sum w^2)/2
    const float den   = fmaxf(0.5f * (1.0f - sq), 0.0f) + EPSF;
    const float ratio = nb * __builtin_amdgcn_rcpf(den);
    const float rho   = 1.0f - exp2f(ratio * (-8.0f * LOG2E));
    if (g == 0) out[p] = rho;
}

extern "C" void kernel_launch(void* const* d_in, const int* in_sizes, int n_in,
                              void* d_out, int out_size, void* d_ws, size_t ws_size,
                              hipStream_t stream) {
    const float* points = (const float*)d_in[0];
    const float* seeds  = (const float*)d_in[1];
    const float* w_raw  = (const float*)d_in[2];
    const float* theta  = (const float*)d_in[3];
    const float* a_raw  = (const float*)d_in[4];
    float* out = (float*)d_out;

    const int N = in_sizes[0] / 2;              // 65536
    const int grid = (N + PPB - 1) / PPB;       // 1024 blocks, 4/CU exact

    voronoi_v8<<<grid, BLOCK, 0, stream>>>(points, seeds, w_raw, theta, a_raw,
                                           out, N);
}

// Round 9
// 19.265 us; speedup vs baseline: 1.2729x; 1.2729x over previous
//
#include <hip/hip_runtime.h>
#include <math.h>

// VoronoiDecoder: N=65536 x S=32. 8 lanes/point, 4 seeds/lane, 512-thr blocks,
// 64 points/block, grid=1024 (4 blocks/CU by LDS). All 70 pair-sigmoids per
// thread via a CONFLICT-FREE LDS table:
//   - coarse step (16 quant-units) + in-word lerp: u32 packs bf16(sigma) and
//     bf16(delta_sigma/16); B = fmaf(frac, slope, base) after ONE ds_read_b32.
//   - x16 bank replication: entry i, copy c at word (i<<4)|c, lane reads copy
//     lane&15 -> <=2-way bank aliasing (free) for ANY index distribution.
// No launch_bounds min-wave pin (R4/R8 spill trap). 16.5KB table + 20.5KB
// slabs + metrics ~= 37.7KB -> 4 blocks/CU resident, 32 waves/CU.

#define LOG2E  1.4426950408889634f
#define EPSF   1e-8f
#define TSC    4096.0f          // distance quant units per 1.0
#define NTAB   258              // idx <= 256, +1 lerp partner
#define BLOCK  512
#define PPB    64               // points per block
#define SSTR   40               // slab row stride (words): 2-way banks = free

__global__ __launch_bounds__(BLOCK) void voronoi_v9(
    const float* __restrict__ points,   // (N,2)
    const float* __restrict__ seeds,    // (32,2)
    const float* __restrict__ w_raw,    // (1,)
    const float* __restrict__ theta,    // (32,)
    const float* __restrict__ a_raw,    // (32,)
    float* __restrict__ out,            // (N,)
    int N)
{
    __shared__ unsigned s_tab[NTAB * 16];   // replicated packed table
    __shared__ unsigned s_ii[PPB * SSTR];   // quantized d (plain index)
    __shared__ float    s_ww[PPB * SSTR];
    __shared__ float    s_su[32], s_sv[32], s_m00[32], s_m01[32], s_m11[32];

    const int t = threadIdx.x;

    // uniform band half-width
    const float wr = w_raw[0];
    const float sg = __builtin_amdgcn_rcpf(1.0f + exp2f(wr * (-LOG2E / 5.0f)));
    const float w  = 0.005f + 0.495f * sg;

    // seed metrics, pre-scaled so sqrt lands in quant units (2x folded in m01)
    if (t < 32) {
        const float x  = a_raw[t];
        const float z  = exp2f(2.0f * LOG2E * x);
        const float th = (z - 1.0f) * __builtin_amdgcn_rcpf(z + 1.0f);  // tanh
        const float a  = 0.75f * th + 1.25f;
        const float ia = __builtin_amdgcn_rcpf(a + EPSF);
        const float cs = __cosf(theta[t]);
        const float sn = __sinf(theta[t]);
        const float S2 = TSC * TSC;
        s_m00[t] = (a * cs * cs + ia * sn * sn) * S2;
        s_m01[t] = (2.0f * cs * sn * (ia - a)) * S2;
        s_m11[t] = (a * sn * sn + ia * cs * cs) * S2;
        s_su[t]  = seeds[2 * t];
        s_sv[t]  = seeds[2 * t + 1];
    }
    // packed lerp table: sigma((w - k/256)/0.02) and slope/16, bf16 pair
    if (t < NTAB) {
        const float z0 = fmaf((float)t,       -50.0f / 256.0f, 50.0f * w);
        const float z1 = fmaf((float)(t + 1), -50.0f / 256.0f, 50.0f * w);
        const float y0 = exp2f(-z0 * LOG2E);
        const float y1 = exp2f(-z1 * LOG2E);
        const float sA = 1.0f / (1.0f + y0);
        const float sB = 1.0f / (1.0f + y1);
        const float sl = (sB - sA) * 0.0625f;
        // round-to-nearest-even bf16 packing
        unsigned ua = __float_as_uint(sA);
        ua = (ua + 0x7fffu + ((ua >> 16) & 1u)) >> 16;
        unsigned ub = __float_as_uint(sl);
        ub = (ub + 0x7fffu + ((ub >> 16) & 1u)) >> 16;
        const unsigned pk = ua | (ub << 16);
        const int base = t << 4;
        #pragma unroll
        for (int c = 0; c < 16; ++c) s_tab[base + c] = pk;
    }
    __syncthreads();   // only barrier; slab exchange below is same-wave

    const int pb = t >> 3;              // point slot (0..63)
    const int g  = t & 7;               // seed group
    const int s0 = g * 4;
    const int cc = t & 15;              // table copy for this lane
    const int p  = blockIdx.x * PPB + pb;
    if (p >= N) return;

    const float4 su4  = *(const float4*)&s_su[s0];
    const float4 sv4  = *(const float4*)&s_sv[s0];
    const float4 m004 = *(const float4*)&s_m00[s0];
    const float4 m014 = *(const float4*)&s_m01[s0];
    const float4 m114 = *(const float4*)&s_m11[s0];

    const float2 uv = ((const float2*)points)[p];
    const float u = uv.x, v = uv.y;

    const float EPS_Q = 1e-8f * TSC * TSC;
    float4 d4;
#define DIST(SU, SV, M00, M01, M11, OUTD)                                  \
    {                                                                      \
        float du = u - (SU); du -= rintf(du);                              \
        float dv = v - (SV); dv -= rintf(dv);                              \
        float q = fmaf(du * du, (M00),                                     \
                  fmaf(du * dv, (M01),                                     \
                  fmaf(dv * dv, (M11), EPS_Q)));                           \
        (OUTD) = sqrtf(q);                                                 \
    }
    DIST(su4.x, sv4.x, m004.x, m014.x, m114.x, d4.x)
    DIST(su4.y, sv4.y, m004.y, m014.y, m114.y, d4.y)
    DIST(su4.z, sv4.z, m004.z, m014.z, m114.z, d4.z)
    DIST(su4.w, sv4.w, m004.w, m014.w, m114.w, d4.w)

    // softmax over 32 seeds (exponents bounded below ~ -29; no max-sub)
    const float cE = -(20.0f * LOG2E) / TSC;
    float4 e4;
    e4.x = exp2f(d4.x * cE);
    e4.y = exp2f(d4.y * cE);
    e4.z = exp2f(d4.z * cE);
    e4.w = exp2f(d4.w * cE);
    float Z = (e4.x + e4.y) + (e4.z + e4.w);
    Z += __shfl_xor(Z, 1, 64);
    Z += __shfl_xor(Z, 2, 64);
    Z += __shfl_xor(Z, 4, 64);
    const float rcpZ = __builtin_amdgcn_rcpf(Z);
    float4 w4;
    w4.x = e4.x * rcpZ; w4.y = e4.y * rcpZ;
    w4.z = e4.z * rcpZ; w4.w = e4.w * rcpZ;
    float sumsq = w4.x * w4.x;
    sumsq = fmaf(w4.y, w4.y, sumsq);
    sumsq = fmaf(w4.z, w4.z, sumsq);
    sumsq = fmaf(w4.w, w4.w, sumsq);

    // quantize d (round-to-nearest; max 4096)
    uint4 ii;
    ii.x = (unsigned)(d4.x + 0.5f);
    ii.y = (unsigned)(d4.y + 0.5f);
    ii.z = (unsigned)(d4.z + 0.5f);
    ii.w = (unsigned)(d4.w + 0.5f);

    // stage to this point's slab row (same-wave exchange, no barrier)
    unsigned* db = &s_ii[pb * SSTR];
    float*    wb = &s_ww[pb * SSTR];
    *(uint4*) (db + s0) = ii;
    *(float4*)(wb + s0) = w4;

    // pair: diff -> (idx, frac) -> one conflict-free ds_read_b32 -> lerp
#define TBODY(IA, IB, WJ, ACC)                                             \
    {                                                                      \
        const unsigned hi = (IA) > (IB) ? (IA) : (IB);                     \
        const unsigned lo = (IA) > (IB) ? (IB) : (IA);                     \
        const unsigned df = hi - lo;                                       \
        const unsigned pk = s_tab[((df >> 4) << 4) + cc];                  \
        const float fr    = (float)(df & 15u);                             \
        const float base  = __uint_as_float(pk << 16);                     \
        const float slope = __uint_as_float(pk & 0xffff0000u);             \
        const float B     = fmaf(fr, slope, base);                         \
        (ACC) = fmaf((WJ), B, (ACC));                                      \
    }

    // 6 in-lane pairs
    float b0, b1, b2, b3;
    b0 = 0.0f; b1 = 0.0f; b2 = 0.0f; b3 = 0.0f;
    TBODY(ii.x, ii.y, w4.y, b0)
    TBODY(ii.x, ii.z, w4.z, b0)
    TBODY(ii.x, ii.w, w4.w, b0)
    TBODY(ii.y, ii.z, w4.z, b1)
    TBODY(ii.y, ii.w, w4.w, b1)
    TBODY(ii.z, ii.w, w4.w, b2)

#define ROT(R)                                                             \
    {                                                                      \
        const int gj = ((g + (R)) & 7) * 4;                                \
        const uint4  ij = *(const uint4*) (db + gj);                       \
        const float4 wj = *(const float4*)(wb + gj);                       \
        TBODY(ii.x, ij.x, wj.x, b0)                                        \
        TBODY(ii.x, ij.y, wj.y, b0)                                        \
        TBODY(ii.x, ij.z, wj.z, b0)                                        \
        TBODY(ii.x, ij.w, wj.w, b0)                                        \
        TBODY(ii.y, ij.x, wj.x, b1)                                        \
        TBODY(ii.y, ij.y, wj.y, b1)                                        \
        TBODY(ii.y, ij.z, wj.z, b1)                                        \
        TBODY(ii.y, ij.w, wj.w, b1)                                        \
        TBODY(ii.z, ij.x, wj.x, b2)                                        \
        TBODY(ii.z, ij.y, wj.y, b2)                                        \
        TBODY(ii.z, ij.z, wj.z, b2)                                        \
        TBODY(ii.z, ij.w, wj.w, b2)                                        \
        TBODY(ii.w, ij.x, wj.x, b3)                                        \
        TBODY(ii.w, ij.y, wj.y, b3)                                        \
        TBODY(ii.w, ij.z, wj.z, b3)                                        \
        TBODY(ii.w, ij.w, wj.w, b3)                                        \
    }
    ROT(1)
    ROT(2)
    ROT(3)
    if (g < 4) {        // r=4 full weight on half the lanes (exact coverage)
        ROT(4)
    }

    float accb = w4.x * b0;
    accb = fmaf(w4.y, b1, accb);
    accb = fmaf(w4.z, b2, accb);
    accb = fmaf(w4.w, b3, accb);

    // reduce over the point's 8 lanes
    float nb = accb, sq = sumsq;
    nb += __shfl_xor(nb, 1, 64);  sq += __shfl_xor(sq, 1, 64);
    nb += __shfl_xor(nb, 2, 64);  sq += __shfl_xor(sq, 2, 64);
    nb += __shfl_xor(nb, 4, 64);  sq += __shfl_xor(sq, 4, 64);

    // pair mass: sum_{i<j} w_i w_j = (1 - sum w^2)/2
    const float den   = fmaxf(0.5f * (1.0f - sq), 0.0f) + EPSF;
    const float ratio = nb * __builtin_amdgcn_rcpf(den);
    const float rho   = 1.0f - exp2f(ratio * (-8.0f * LOG2E));
    if (g == 0) out[p] = rho;
}

extern "C" void kernel_launch(void* const* d_in, const int* in_sizes, int n_in,
                              void* d_out, int out_size, void* d_ws, size_t ws_size,
                              hipStream_t stream) {
    const float* points = (const float*)d_in[0];
    const float* seeds  = (const float*)d_in[1];
    const float* w_raw  = (const float*)d_in[2];
    const float* theta  = (const float*)d_in[3];
    const float* a_raw  = (const float*)d_in[4];
    float* out = (float*)d_out;

    const int N = in_sizes[0] / 2;              // 65536
    const int grid = (N + PPB - 1) / PPB;       // 1024 blocks

    voronoi_v9<<<grid, BLOCK, 0, stream>>>(points, seeds, w_raw, theta, a_raw,
                                           out, N);
}